// Round 11
// baseline (210.436 us; speedup 1.0000x reference)
//
#include <hip/hip_runtime.h>
#include <hip/hip_bf16.h>
#include <math.h>

using bf16 = __hip_bfloat16;
typedef __attribute__((ext_vector_type(8))) short short8;   // 8 bf16 = 4 VGPRs (MFMA A/B frag)
typedef __attribute__((ext_vector_type(4))) float floatx4;  // MFMA C/D frag

#define MFMA16(a, b, c) __builtin_amdgcn_mfma_f32_16x16x32_bf16((a), (b), (c), 0, 0, 0)

// async global->LDS, 16B/lane; LDS dest = wave-uniform base + lane*16 [m97]
__device__ __forceinline__ void gll16(const void* g, void* l) {
  __builtin_amdgcn_global_load_lds((__attribute__((address_space(1))) void*)(uintptr_t)g,
                                   (__attribute__((address_space(3))) void*)l, 16, 0, 0);
}

// ---------------------------------------------------------------------------
// Detect dtype (fp32 vs bf16) + cast bias. One block.
// ---------------------------------------------------------------------------
__global__ void detect_bias_k(const unsigned short* __restrict__ x,
                              const void* __restrict__ bsrc,
                              bf16* __restrict__ bdst, int* __restrict__ flag) {
  __shared__ int cnt;
  if (threadIdx.x == 0) cnt = 0;
  __syncthreads();
  int local = 0;
  for (int i = threadIdx.x; i < 8192; i += 256) {
    unsigned short v = x[2 * i];  // low half of float i if fp32
    if (((v >> 7) & 0xFF) == 0xFF) local++;
  }
  if (local) atomicAdd(&cnt, local);
  __syncthreads();
  int f = (cnt > 0) ? 1 : 0;
  if (threadIdx.x == 0) *flag = f;
  for (int i = threadIdx.x; i < 1024; i += 256)
    bdst[i] = f ? __float2bfloat16(((const float*)bsrc)[i]) : ((const bf16*)bsrc)[i];
}

// ---------------------------------------------------------------------------
// Fused prep: z<2 -> x cast halves; z=2..5 -> transpose Wq/Wk/Wv/Wp to bf16.
// grid (32,32,6), block (32,8).
// ---------------------------------------------------------------------------
__global__ __launch_bounds__(256) void prep_k(const void* __restrict__ xin,
                                              bf16* __restrict__ xb,
                                              const void* __restrict__ W0,
                                              const void* __restrict__ W1,
                                              const void* __restrict__ W2,
                                              const void* __restrict__ W3,
                                              bf16* __restrict__ Wt,
                                              bf16* __restrict__ Wpt,
                                              const int* __restrict__ flag) {
  bool f32 = (*flag != 0);
  int z = blockIdx.z;
  if (z < 2) {  // x cast
    int tid = threadIdx.y * 32 + threadIdx.x;
    int blockLin = z * 1024 + blockIdx.y * 32 + blockIdx.x;
    int idx = blockLin * 2048 + tid * 8;
    if (f32) {
      const float4* p = reinterpret_cast<const float4*>((const float*)xin + idx);
      float4 a = p[0], b = p[1];
      union { bf16 h[8]; uint4 u; } U;
      U.h[0] = __float2bfloat16(a.x); U.h[1] = __float2bfloat16(a.y);
      U.h[2] = __float2bfloat16(a.z); U.h[3] = __float2bfloat16(a.w);
      U.h[4] = __float2bfloat16(b.x); U.h[5] = __float2bfloat16(b.y);
      U.h[6] = __float2bfloat16(b.z); U.h[7] = __float2bfloat16(b.w);
      *reinterpret_cast<uint4*>(xb + idx) = U.u;
    } else {
      *reinterpret_cast<uint4*>(xb + idx) =
          *reinterpret_cast<const uint4*>((const bf16*)xin + idx);
    }
    return;
  }
  const void* src = (z == 2) ? W0 : (z == 3) ? W1 : (z == 4) ? W2 : W3;
  bf16* dst = (z == 5) ? Wpt : (Wt + (size_t)(z - 2) * 1024 * 1024);
  __shared__ float tsh[32][33];
  int tx = threadIdx.x, ty = threadIdx.y;
  int k0 = blockIdx.y * 32, n0 = blockIdx.x * 32;
  for (int i = 0; i < 4; i++) {
    size_t off = (size_t)(k0 + ty + i * 8) * 1024 + n0 + tx;
    tsh[ty + i * 8][tx] = f32 ? ((const float*)src)[off]
                              : __bfloat162float(((const bf16*)src)[off]);
  }
  __syncthreads();
  for (int i = 0; i < 4; i++)
    dst[(size_t)(n0 + ty + i * 8) * 1024 + k0 + tx] = __float2bfloat16(tsh[tx][ty + i * 8]);
}

// ---------------------------------------------------------------------------
// Transpose V region of QKV into VT[bh][64][2048]. 64x64 tiles: 128B
// contiguous global segments both phases; LDS pitch 66 (33 words == 1 mod 32
// -> conflict-free). grid (32 s-tiles, 32 bh), block (64,8).
// ---------------------------------------------------------------------------
__global__ __launch_bounds__(512) void vtrans_k(const bf16* __restrict__ QKV,
                                                bf16* __restrict__ VT) {
  __shared__ bf16 t[64][66];
  int tx = threadIdx.x, ty = threadIdx.y;
  int s0 = blockIdx.x * 64, bh = blockIdx.y;
  int b = bh >> 4, h = bh & 15;
  size_t rowb = (size_t)b * 2048;
  int hv = 2048 + h * 64;
#pragma unroll
  for (int i = 0; i < 8; i++)
    t[i * 8 + ty][tx] = QKV[(rowb + s0 + i * 8 + ty) * 3072 + hv + tx];
  __syncthreads();
#pragma unroll
  for (int i = 0; i < 8; i++)
    VT[((size_t)bh * 64 + i * 8 + ty) * 2048 + s0 + tx] = t[tx][i * 8 + ty];
}

// ---------------------------------------------------------------------------
// GEMM 128x128 tile. R11: 2-phase counted-overlap (T3-minimum), BK=32 dbuf.
// Old loop staged BETWEEN two barriers -> vmcnt(0) drained right after issue
// (zero cross-tile overlap; every step ate full load latency). New loop:
// STAGE(next) -> frag ds_reads -> MFMA -> __syncthreads (compiler's
// pre-barrier vmcnt(0) is the drain: loads had the whole compute phase to
// land). Same LDS bytes (32KB: dbuf x BK=32 == old kh x 2), same 3
// blocks/CU, same frag math, same barrier count (1/step x 32 = 2/step x 16).
// WAR-safe: stage target = buffer read two phases ago, behind a barrier.
// ---------------------------------------------------------------------------
__global__ __launch_bounds__(256) void gemm_bt128(const bf16* __restrict__ A, int lda,
                                                  const bf16* __restrict__ Bt, int ldb,
                                                  void* __restrict__ C, int ldc,
                                                  const bf16* __restrict__ bias, int K,
                                                  const int* __restrict__ outflag) {
  __shared__ bf16 As[2][128 * 32];  // [dbuf][row*32], BK=32
  __shared__ bf16 Bs[2][128 * 32];
  int t = threadIdx.x;
  int w = t >> 6, lane = t & 63;
  int g = lane >> 4, c = lane & 15;
  int wm = (w >> 1) * 64, wn = (w & 1) * 64;
  int m0 = blockIdx.y * 128, n0 = blockIdx.x * 128;

  int sr = w * 16 + (lane >> 2);  // 0..63
  int sc = (lane & 3) * 8;
  const bf16* Ab = A + (size_t)(m0 + sr) * lda + sc;
  const bf16* Bb = Bt + (size_t)(n0 + sr) * ldb + sc;
  int lofs = (w * 16) * 32;

#define STG128(d, kk)                                                 \
  {                                                                   \
    gll16(Ab + (kk), &As[d][lofs]);                                   \
    gll16(Ab + (kk) + (size_t)64 * lda, &As[d][lofs + 64 * 32]);      \
    gll16(Bb + (kk), &Bs[d][lofs]);                                   \
    gll16(Bb + (kk) + (size_t)64 * ldb, &Bs[d][lofs + 64 * 32]);      \
  }

  floatx4 acc[4][4] = {};
  int nsteps = K >> 5;  // 32

  STG128(0, 0);
  __syncthreads();
  int cur = 0;
  for (int s = 0; s < nsteps - 1; ++s) {
    STG128(cur ^ 1, (s + 1) * 32);
    short8 af[4], bf[4];
#pragma unroll
    for (int i = 0; i < 4; i++) {
      af[i] = *reinterpret_cast<const short8*>(&As[cur][(wm + i * 16 + c) * 32 + g * 8]);
      bf[i] = *reinterpret_cast<const short8*>(&Bs[cur][(wn + i * 16 + c) * 32 + g * 8]);
    }
    __builtin_amdgcn_s_setprio(1);
#pragma unroll
    for (int i = 0; i < 4; i++)
#pragma unroll
      for (int j = 0; j < 4; j++) acc[i][j] = MFMA16(af[i], bf[j], acc[i][j]);
    __builtin_amdgcn_s_setprio(0);
    __syncthreads();  // drains vmcnt -> next buffer ready; WAR-safe for next stage
    cur ^= 1;
  }
  {
    short8 af[4], bf[4];
#pragma unroll
    for (int i = 0; i < 4; i++) {
      af[i] = *reinterpret_cast<const short8*>(&As[cur][(wm + i * 16 + c) * 32 + g * 8]);
      bf[i] = *reinterpret_cast<const short8*>(&Bs[cur][(wn + i * 16 + c) * 32 + g * 8]);
    }
#pragma unroll
    for (int i = 0; i < 4; i++)
#pragma unroll
      for (int j = 0; j < 4; j++) acc[i][j] = MFMA16(af[i], bf[j], acc[i][j]);
  }
#undef STG128

  bool f32out = (outflag != nullptr) && (*outflag != 0);
#pragma unroll
  for (int i = 0; i < 4; i++) {
    int rbase = m0 + wm + i * 16 + g * 4;
#pragma unroll
    for (int j = 0; j < 4; j++) {
      int col = n0 + wn + j * 16 + c;
      float bv = bias ? __bfloat162float(bias[col]) : 0.f;
#pragma unroll
      for (int r = 0; r < 4; r++) {
        size_t off = (size_t)(rbase + r) * ldc + col;
        float v = acc[i][j][r] + bv;
        if (f32out) ((float*)C)[off] = v;
        else ((bf16*)C)[off] = __float2bfloat16(v);
      }
    }
  }
}

// ---------------------------------------------------------------------------
// GEMM 128x64 tile (gemm2). R11: same 2-phase BK=32 dbuf overlap.
// ---------------------------------------------------------------------------
__global__ __launch_bounds__(256) void gemm_bt64(const bf16* __restrict__ A, int lda,
                                                 const bf16* __restrict__ Bt, int ldb,
                                                 void* __restrict__ C, int ldc,
                                                 const bf16* __restrict__ bias, int K,
                                                 const int* __restrict__ outflag) {
  __shared__ bf16 As[2][128 * 32];
  __shared__ bf16 Bs[2][64 * 32];
  int t = threadIdx.x;
  int w = t >> 6, lane = t & 63;
  int g = lane >> 4, c = lane & 15;
  int wm = (w >> 1) * 64, wn = (w & 1) * 32;
  int m0 = blockIdx.y * 128, n0 = blockIdx.x * 64;

  int sr = w * 16 + (lane >> 2);  // 0..63
  int sc = (lane & 3) * 8;
  const bf16* Ab = A + (size_t)(m0 + sr) * lda + sc;
  const bf16* Bb = Bt + (size_t)(n0 + sr) * ldb + sc;
  int lofs = (w * 16) * 32;

#define STG64(d, kk)                                                  \
  {                                                                   \
    gll16(Ab + (kk), &As[d][lofs]);                                   \
    gll16(Ab + (kk) + (size_t)64 * lda, &As[d][lofs + 64 * 32]);      \
    gll16(Bb + (kk), &Bs[d][lofs]);                                   \
  }

  floatx4 acc[4][2] = {};
  int nsteps = K >> 5;  // 32

  STG64(0, 0);
  __syncthreads();
  int cur = 0;
  for (int s = 0; s < nsteps - 1; ++s) {
    STG64(cur ^ 1, (s + 1) * 32);
    short8 af[4], bf[2];
#pragma unroll
    for (int i = 0; i < 4; i++)
      af[i] = *reinterpret_cast<const short8*>(&As[cur][(wm + i * 16 + c) * 32 + g * 8]);
#pragma unroll
    for (int j = 0; j < 2; j++)
      bf[j] = *reinterpret_cast<const short8*>(&Bs[cur][(wn + j * 16 + c) * 32 + g * 8]);
    __builtin_amdgcn_s_setprio(1);
#pragma unroll
    for (int i = 0; i < 4; i++)
#pragma unroll
      for (int j = 0; j < 2; j++) acc[i][j] = MFMA16(af[i], bf[j], acc[i][j]);
    __builtin_amdgcn_s_setprio(0);
    __syncthreads();
    cur ^= 1;
  }
  {
    short8 af[4], bf[2];
#pragma unroll
    for (int i = 0; i < 4; i++)
      af[i] = *reinterpret_cast<const short8*>(&As[cur][(wm + i * 16 + c) * 32 + g * 8]);
#pragma unroll
    for (int j = 0; j < 2; j++)
      bf[j] = *reinterpret_cast<const short8*>(&Bs[cur][(wn + j * 16 + c) * 32 + g * 8]);
#pragma unroll
    for (int i = 0; i < 4; i++)
#pragma unroll
      for (int j = 0; j < 2; j++) acc[i][j] = MFMA16(af[i], bf[j], acc[i][j]);
  }
#undef STG64

  bool f32out = (outflag != nullptr) && (*outflag != 0);
#pragma unroll
  for (int i = 0; i < 4; i++) {
    int rbase = m0 + wm + i * 16 + g * 4;
#pragma unroll
    for (int j = 0; j < 2; j++) {
      int col = n0 + wn + j * 16 + c;
      float bv = bias ? __bfloat162float(bias[col]) : 0.f;
#pragma unroll
      for (int r = 0; r < 4; r++) {
        size_t off = (size_t)(rbase + r) * ldc + col;
        float v = acc[i][j][r] + bv;
        if (f32out) ((float*)C)[off] = v;
        else ((bf16*)C)[off] = __float2bfloat16(v);
      }
    }
  }
}

// ---------------------------------------------------------------------------
// R10 split-K causal attention (proven: 52.4 -> 43.6 us, occ 25 -> 42%).
// Fixed-offset softmax (exp2(s*scale-23.08), no running max) -> partials
// over disjoint k-ranges exactly additive; qt>=8 splits into 2 half-k
// blocks writing f32 partials; combine_k merges. 768 blocks = 3/CU; every
// block <= 16 tiles. Static LPT triple table (optimal for 2-way splits).
// XCD-local heads preserved. R11 delta: diag branch hoisted (wave-uniform)
// -> masked softmax only on diagonal tiles (~10%); plain path drops
// 16x(add+cmp+cndmask) per wave-tile (VALUBusy was 58%).
// ---------------------------------------------------------------------------
__device__ const int QT_TAB[8][3] = {{15, 15, 0}, {7, 13, 1},  {14, 12, 2}, {14, 10, 3},
                                     {13, 4, 9},  {6, 10, 8},  {12, 11, 8}, {5, 11, 9}};
__device__ const int HF_TAB[8][3] = {{0, 1, 2}, {2, 0, 2}, {0, 0, 2}, {1, 0, 2},
                                     {1, 2, 0}, {2, 1, 0}, {1, 0, 1}, {2, 1, 1}};

__global__ __launch_bounds__(512, 4) void attn_lds2(bf16* __restrict__ QKV,
                                                    const bf16* __restrict__ VT,
                                                    float* __restrict__ Po,
                                                    float* __restrict__ Pl) {
  const int S = 2048, LD = 3072;
  __shared__ bf16 Ks[2][2][64 * 32];
  __shared__ bf16 Vs[2][2][64 * 32];
  __shared__ bf16 Pb[8][16 * 72];

  int t = threadIdx.x, w = t >> 6, lane = t & 63, g = lane >> 4, c = lane & 15;

  // slot decode: 768 blocks; co-resident CU triple = (r, r+256, r+512)
  int r = blockIdx.x + 24 * blockIdx.y;   // hw linear dispatch index
  int xcd = r & 7;
  int s = r >> 3;                          // 0..95 on this XCD
  int r3 = s >> 5;                         // ring 0..2 (CU triple member)
  int u = s & 31;                          // CU index on XCD
  int hg = u >> 3;                         // head group 0..3
  int tri = u & 7;                         // triple id
  int bh = xcd + 8 * hg;                   // XCD-local heads (4/XCD, 2MB K/V)
  int qt = QT_TAB[tri][r3];
  int hf = HF_TAB[tri][r3];                // 0/1 = split half, 2 = unsplit

  int b = bh >> 4, h = bh & 15;
  int qbase = qt * 128;
  size_t rowb = (size_t)b * S;
  int hq = h * 64, hk = 1024 + h * 64;
  const bf16* Vt = VT + (size_t)bh * 64 * 2048;
  bf16* pb = Pb[w];

  int nkt = 2 * qt + 2;
  int kb0 = (hf == 1) ? (qt + 1) : 0;
  int kb1 = (hf == 0) ? (qt + 1) : nkt;

  int su = (w & 3) * 16 + (lane >> 2);
  int sc = (lane & 3) * 8;
  const bf16* Kg = &QKV[(rowb + su) * LD + hk + sc];
  const bf16* Vg = &Vt[(size_t)su * 2048 + sc];
  int sofs = ((w & 3) * 16) * 32;

  short8 qf[2];
#pragma unroll
  for (int hfr = 0; hfr < 2; hfr++)
    qf[hfr] = *reinterpret_cast<const short8*>(
        &QKV[(rowb + qbase + w * 16 + c) * LD + hq + hfr * 32 + g * 8]);

  floatx4 o[4] = {};
  float lsum = 0.f;
  int qrow = qbase + w * 16 + c;  // this lane's q-row for the S^T fragment

  {
    size_t k0off = (size_t)kb0 * 64;
    if (w < 4) {
      gll16(Kg + k0off * LD, &Ks[0][0][sofs]);
      gll16(Kg + k0off * LD + 32, &Ks[0][1][sofs]);
    } else {
      gll16(Vg + k0off, &Vs[0][0][sofs]);
      gll16(Vg + k0off + 32, &Vs[0][1][sofs]);
    }
  }

  for (int kt = kb0; kt < kb1; kt++) {
    int kbase = kt * 64;
    int cur = (kt - kb0) & 1;
    __syncthreads();
    if (kt + 1 < kb1) {
      int nb = cur ^ 1;
      size_t kofs = (size_t)(kbase + 64);
      if (w < 4) {
        gll16(Kg + kofs * LD, &Ks[nb][0][sofs]);
        gll16(Kg + kofs * LD + 32, &Ks[nb][1][sofs]);
      } else {
        gll16(Vg + kofs, &Vs[nb][0][sofs]);
        gll16(Vg + kofs + 32, &Vs[nb][1][sofs]);
      }
    }

    short8 kf[4][2];
#pragma unroll
    for (int nt = 0; nt < 4; nt++)
#pragma unroll
      for (int hfr = 0; hfr < 2; hfr++)
        kf[nt][hfr] =
            *reinterpret_cast<const short8*>(&Ks[cur][hfr][(nt * 16 + c) * 32 + g * 8]);

    // S^T tile: sv[nt][rr] = S[k = kbase + nt*16 + g*4 + rr][q = qrow]
    floatx4 sv[4];
    __builtin_amdgcn_s_setprio(1);
#pragma unroll
    for (int nt = 0; nt < 4; nt++) {
      floatx4 z = {};
      z = MFMA16(kf[nt][0], qf[0], z);
      z = MFMA16(kf[nt][1], qf[1], z);
      sv[nt] = z;
    }
    __builtin_amdgcn_s_setprio(0);

    bool diag = (kbase + 63 > qbase + w * 16);  // wave-uniform -> s_cbranch
    if (!diag) {
#pragma unroll
      for (int nt = 0; nt < 4; nt++)
#pragma unroll
        for (int rr = 0; rr < 4; rr++) {
          float p = exp2f(fmaf(sv[nt][rr], 0.18033688f, -23.083120f));
          lsum += p;
          sv[nt][rr] = p;
        }
    } else {
#pragma unroll
      for (int nt = 0; nt < 4; nt++) {
        int kcol0 = kbase + nt * 16 + g * 4;
#pragma unroll
        for (int rr = 0; rr < 4; rr++) {
          float arg = fmaf(sv[nt][rr], 0.18033688f, -23.083120f);
          if (kcol0 + rr > qrow) arg = -1e30f;
          float p = exp2f(arg);
          lsum += p;
          sv[nt][rr] = p;
        }
      }
    }

    // P[q=c][k]: each lane stores 4 consecutive k as one b64
#pragma unroll
    for (int nt = 0; nt < 4; nt++) {
      union { bf16 h4[4]; uint2 u2; } U;
      U.h4[0] = __float2bfloat16(sv[nt][0]);
      U.h4[1] = __float2bfloat16(sv[nt][1]);
      U.h4[2] = __float2bfloat16(sv[nt][2]);
      U.h4[3] = __float2bfloat16(sv[nt][3]);
      *reinterpret_cast<uint2*>(&pb[c * 72 + nt * 16 + g * 4]) = U.u2;
    }
    asm volatile("s_waitcnt lgkmcnt(0)" ::: "memory");
    short8 pf0 = *reinterpret_cast<const short8*>(&pb[c * 72 + g * 8]);
    short8 pf1 = *reinterpret_cast<const short8*>(&pb[c * 72 + 32 + g * 8]);

    __builtin_amdgcn_s_setprio(1);
#pragma unroll
    for (int dt = 0; dt < 4; dt++) {
      short8 vf0 = *reinterpret_cast<const short8*>(&Vs[cur][0][(dt * 16 + c) * 32 + g * 8]);
      short8 vf1 = *reinterpret_cast<const short8*>(&Vs[cur][1][(dt * 16 + c) * 32 + g * 8]);
      o[dt] = MFMA16(pf0, vf0, o[dt]);
      o[dt] = MFMA16(pf1, vf1, o[dt]);
    }
    __builtin_amdgcn_s_setprio(0);
  }

  // full row-sum for q-row c (butterfly over the 4 g-groups: all lanes get it)
  lsum += __shfl_xor(lsum, 16);
  lsum += __shfl_xor(lsum, 32);

  if (hf == 2) {
    float lrec = 1.0f / lsum;
    float l_r[4];
#pragma unroll
    for (int rr = 0; rr < 4; rr++) l_r[rr] = __shfl(lrec, g * 4 + rr);
#pragma unroll
    for (int dt = 0; dt < 4; dt++)
#pragma unroll
      for (int rr = 0; rr < 4; rr++) {
        float v = o[dt][rr] * l_r[rr];
        QKV[(rowb + qbase + w * 16 + g * 4 + rr) * LD + hq + dt * 16 + c] =
            __float2bfloat16(v);
      }
  } else {
    // write raw partials (additive): o f32 + per-row lsum
    int slot = (bh * 8 + (qt - 8)) * 2 + hf;
    float* po = Po + (size_t)slot * (128 * 64);
    float* pl = Pl + slot * 128;
    if (g == 0) pl[w * 16 + c] = lsum;
#pragma unroll
    for (int dt = 0; dt < 4; dt++)
#pragma unroll
      for (int rr = 0; rr < 4; rr++)
        po[(w * 16 + g * 4 + rr) * 64 + dt * 16 + c] = o[dt][rr];
  }
}

// ---------------------------------------------------------------------------
// Combine split-K partials: out = (oA+oB)/(lA+lB) -> Q region bf16.
// grid (8 qt-slots, 32 bh), 256 thr.
// ---------------------------------------------------------------------------
__global__ __launch_bounds__(256) void combine_k(const float* __restrict__ Po,
                                                 const float* __restrict__ Pl,
                                                 bf16* __restrict__ QKV) {
  int qi = blockIdx.x;        // qt = 8 + qi
  int bh = blockIdx.y;
  int b = bh >> 4, h = bh & 15;
  int qt = 8 + qi;
  int slot = (bh * 8 + qi) * 2;
  const float* oA = Po + (size_t)slot * (128 * 64);
  const float* oB = oA + 128 * 64;
  const float* lA = Pl + slot * 128;
  const float* lB = lA + 128;
  int t = threadIdx.x;
#pragma unroll
  for (int i = 0; i < 32; i++) {
    int idx = t + i * 256;    // 0..8191
    int row = idx >> 6, d = idx & 63;
    float l = lA[row] + lB[row];
    float v = (oA[idx] + oB[idx]) / l;
    QKV[((size_t)b * 2048 + qt * 128 + row) * 3072 + h * 64 + d] = __float2bfloat16(v);
  }
}

// ---------------------------------------------------------------------------
extern "C" void kernel_launch(void* const* d_in, const int* in_sizes, int n_in,
                              void* d_out, int out_size, void* d_ws, size_t ws_size,
                              hipStream_t stream) {
  char* ws = (char*)d_ws;
  const size_t MB = 1024 * 1024;
  int* flag = (int*)ws;                       // 4 B
  bf16* bias = (bf16*)(ws + 4096);            // 2 KB
  bf16* xb = (bf16*)(ws + 1 * MB);            // [4096][1024]  8 MB (reused as VT)
  bf16* Wt = (bf16*)(ws + 9 * MB);            // [3072][1024]  6 MB
  bf16* Wpt = (bf16*)(ws + 15 * MB);          // [1024][1024]  2 MB
  bf16* QKV = (bf16*)(ws + 17 * MB);          // [4096][3072] 24 MB
  bf16* VT = xb;                              // xb dead after gemm1
  // split-K partials: o needs 32*8*2*128*64*4 = 16 MB. d_out (f32 out =
  // 16 MB) is dead until gemm2 -> reuse it when big enough; else ws tail.
  float* Pl = (float*)(ws + 41 * MB);         // 256 KB lsum partials
  float* Po = (out_size >= (int)(16 * MB)) ? (float*)d_out
                                           : (float*)(ws + 42 * MB);

  detect_bias_k<<<1, 256, 0, stream>>>((const unsigned short*)d_in[0], d_in[5], bias, flag);
  prep_k<<<dim3(32, 32, 6), dim3(32, 8), 0, stream>>>(d_in[0], xb, d_in[1], d_in[2],
                                                      d_in[3], d_in[4], Wt, Wpt, flag);

  // QKV = xb @ [Wq|Wk|Wv] : M=4096, N=3072, K=1024 (2-phase overlap)
  gemm_bt128<<<dim3(24, 32), 256, 0, stream>>>(xb, 1024, Wt, 1024, QKV, 3072, nullptr,
                                               1024, nullptr);
  // V^T into (dead) xb region
  vtrans_k<<<dim3(32, 32), dim3(64, 8), 0, stream>>>(QKV, VT);
  // split-K attention: 768 blocks, every block <= 16 k-tiles
  attn_lds2<<<dim3(24, 32), 512, 0, stream>>>(QKV, VT, Po, Pl);
  // merge split partials into Q region
  combine_k<<<dim3(8, 32), 256, 0, stream>>>(Po, Pl, QKV);
  // out = attn_out @ Wp + bp : M=4096, N=1024, K=1024 (2-phase overlap)
  gemm_bt64<<<dim3(16, 32), 256, 0, stream>>>(QKV, 3072, Wpt, 1024, d_out, 1024, bias,
                                              1024, flag);
}

// Round 12
// 198.395 us; speedup vs baseline: 1.0607x; 1.0607x over previous
//
#include <hip/hip_runtime.h>
#include <hip/hip_bf16.h>
#include <math.h>

using bf16 = __hip_bfloat16;
typedef __attribute__((ext_vector_type(8))) short short8;   // 8 bf16 = 4 VGPRs (MFMA A/B frag)
typedef __attribute__((ext_vector_type(4))) float floatx4;  // MFMA C/D frag

#define MFMA16(a, b, c) __builtin_amdgcn_mfma_f32_16x16x32_bf16((a), (b), (c), 0, 0, 0)

// async global->LDS, 16B/lane; LDS dest = wave-uniform base + lane*16 [m97]
__device__ __forceinline__ void gll16(const void* g, void* l) {
  __builtin_amdgcn_global_load_lds((__attribute__((address_space(1))) void*)(uintptr_t)g,
                                   (__attribute__((address_space(3))) void*)l, 16, 0, 0);
}

// ---------------------------------------------------------------------------
// Detect dtype (fp32 vs bf16) + cast bias. One block.
// ---------------------------------------------------------------------------
__global__ void detect_bias_k(const unsigned short* __restrict__ x,
                              const void* __restrict__ bsrc,
                              bf16* __restrict__ bdst, int* __restrict__ flag) {
  __shared__ int cnt;
  if (threadIdx.x == 0) cnt = 0;
  __syncthreads();
  int local = 0;
  for (int i = threadIdx.x; i < 8192; i += 256) {
    unsigned short v = x[2 * i];  // low half of float i if fp32
    if (((v >> 7) & 0xFF) == 0xFF) local++;
  }
  if (local) atomicAdd(&cnt, local);
  __syncthreads();
  int f = (cnt > 0) ? 1 : 0;
  if (threadIdx.x == 0) *flag = f;
  for (int i = threadIdx.x; i < 1024; i += 256)
    bdst[i] = f ? __float2bfloat16(((const float*)bsrc)[i]) : ((const bf16*)bsrc)[i];
}

// ---------------------------------------------------------------------------
// Fused prep: z<2 -> x cast halves; z=2..5 -> transpose Wq/Wk/Wv/Wp to bf16.
// grid (32,32,6), block (32,8).
// ---------------------------------------------------------------------------
__global__ __launch_bounds__(256) void prep_k(const void* __restrict__ xin,
                                              bf16* __restrict__ xb,
                                              const void* __restrict__ W0,
                                              const void* __restrict__ W1,
                                              const void* __restrict__ W2,
                                              const void* __restrict__ W3,
                                              bf16* __restrict__ Wt,
                                              bf16* __restrict__ Wpt,
                                              const int* __restrict__ flag) {
  bool f32 = (*flag != 0);
  int z = blockIdx.z;
  if (z < 2) {  // x cast
    int tid = threadIdx.y * 32 + threadIdx.x;
    int blockLin = z * 1024 + blockIdx.y * 32 + blockIdx.x;
    int idx = blockLin * 2048 + tid * 8;
    if (f32) {
      const float4* p = reinterpret_cast<const float4*>((const float*)xin + idx);
      float4 a = p[0], b = p[1];
      union { bf16 h[8]; uint4 u; } U;
      U.h[0] = __float2bfloat16(a.x); U.h[1] = __float2bfloat16(a.y);
      U.h[2] = __float2bfloat16(a.z); U.h[3] = __float2bfloat16(a.w);
      U.h[4] = __float2bfloat16(b.x); U.h[5] = __float2bfloat16(b.y);
      U.h[6] = __float2bfloat16(b.z); U.h[7] = __float2bfloat16(b.w);
      *reinterpret_cast<uint4*>(xb + idx) = U.u;
    } else {
      *reinterpret_cast<uint4*>(xb + idx) =
          *reinterpret_cast<const uint4*>((const bf16*)xin + idx);
    }
    return;
  }
  const void* src = (z == 2) ? W0 : (z == 3) ? W1 : (z == 4) ? W2 : W3;
  bf16* dst = (z == 5) ? Wpt : (Wt + (size_t)(z - 2) * 1024 * 1024);
  __shared__ float tsh[32][33];
  int tx = threadIdx.x, ty = threadIdx.y;
  int k0 = blockIdx.y * 32, n0 = blockIdx.x * 32;
  for (int i = 0; i < 4; i++) {
    size_t off = (size_t)(k0 + ty + i * 8) * 1024 + n0 + tx;
    tsh[ty + i * 8][tx] = f32 ? ((const float*)src)[off]
                              : __bfloat162float(((const bf16*)src)[off]);
  }
  __syncthreads();
  for (int i = 0; i < 4; i++)
    dst[(size_t)(n0 + ty + i * 8) * 1024 + k0 + tx] = __float2bfloat16(tsh[tx][ty + i * 8]);
}

// ---------------------------------------------------------------------------
// Transpose V region of QKV into VT[bh][64][2048]. 64x64 tiles: 128B
// contiguous global segments both phases; LDS pitch 66 (33 words == 1 mod 32
// -> conflict-free). grid (32 s-tiles, 32 bh), block (64,8).
// ---------------------------------------------------------------------------
__global__ __launch_bounds__(512) void vtrans_k(const bf16* __restrict__ QKV,
                                                bf16* __restrict__ VT) {
  __shared__ bf16 t[64][66];
  int tx = threadIdx.x, ty = threadIdx.y;
  int s0 = blockIdx.x * 64, bh = blockIdx.y;
  int b = bh >> 4, h = bh & 15;
  size_t rowb = (size_t)b * 2048;
  int hv = 2048 + h * 64;
#pragma unroll
  for (int i = 0; i < 8; i++)
    t[i * 8 + ty][tx] = QKV[(rowb + s0 + i * 8 + ty) * 3072 + hv + tx];
  __syncthreads();
#pragma unroll
  for (int i = 0; i < 8; i++)
    VT[((size_t)bh * 64 + i * 8 + ty) * 2048 + s0 + tx] = t[tx][i * 8 + ty];
}

// ---------------------------------------------------------------------------
// GEMM 128x128 tile, BK=64 (R3-exact; R6-R11 ledger: 3/CU-128^2 = local
// optimum; swizzle neutral; split/256^2-pipeline/6-per-CU/2-phase all worse).
// ---------------------------------------------------------------------------
__global__ __launch_bounds__(256) void gemm_bt128(const bf16* __restrict__ A, int lda,
                                                  const bf16* __restrict__ Bt, int ldb,
                                                  void* __restrict__ C, int ldc,
                                                  const bf16* __restrict__ bias, int K,
                                                  const int* __restrict__ outflag) {
  __shared__ bf16 As[2][128 * 32];  // [k-half][row][32]
  __shared__ bf16 Bs[2][128 * 32];
  int t = threadIdx.x;
  int w = t >> 6, lane = t & 63;
  int g = lane >> 4, c = lane & 15;
  int wm = (w >> 1) * 64, wn = (w & 1) * 64;
  int m0 = blockIdx.y * 128, n0 = blockIdx.x * 128;

  int sr = w * 32 + (lane >> 2);
  int sc = (lane & 3) * 8;
  const bf16* Ab = A + (size_t)(m0 + sr) * lda + sc;
  const bf16* Bb = Bt + (size_t)(n0 + sr) * ldb + sc;
  int lofs = (w * 32) * 32;  // wave-uniform LDS offset (j=0)

  floatx4 acc[4][4] = {};

  for (int k0 = 0; k0 < K; k0 += 64) {
    __syncthreads();
#pragma unroll
    for (int h = 0; h < 2; h++) {
      gll16(Ab + k0 + h * 32, &As[h][lofs]);
      gll16(Ab + k0 + h * 32 + (size_t)16 * lda, &As[h][lofs + 16 * 32]);
      gll16(Bb + k0 + h * 32, &Bs[h][lofs]);
      gll16(Bb + k0 + h * 32 + (size_t)16 * ldb, &Bs[h][lofs + 16 * 32]);
    }
    __syncthreads();
#pragma unroll
    for (int h = 0; h < 2; h++) {
      short8 af[4], bf[4];
#pragma unroll
      for (int i = 0; i < 4; i++) {
        af[i] = *reinterpret_cast<const short8*>(&As[h][(wm + i * 16 + c) * 32 + g * 8]);
        bf[i] = *reinterpret_cast<const short8*>(&Bs[h][(wn + i * 16 + c) * 32 + g * 8]);
      }
#pragma unroll
      for (int i = 0; i < 4; i++)
#pragma unroll
        for (int j = 0; j < 4; j++) acc[i][j] = MFMA16(af[i], bf[j], acc[i][j]);
    }
  }

  bool f32out = (outflag != nullptr) && (*outflag != 0);
#pragma unroll
  for (int i = 0; i < 4; i++) {
    int rbase = m0 + wm + i * 16 + g * 4;
#pragma unroll
    for (int j = 0; j < 4; j++) {
      int col = n0 + wn + j * 16 + c;
      float bv = bias ? __bfloat162float(bias[col]) : 0.f;
#pragma unroll
      for (int r = 0; r < 4; r++) {
        size_t off = (size_t)(rbase + r) * ldc + col;
        float v = acc[i][j][r] + bv;
        if (f32out) ((float*)C)[off] = v;
        else ((bf16*)C)[off] = __float2bfloat16(v);
      }
    }
  }
}

// ---------------------------------------------------------------------------
// GEMM 128x64 tile, BK=64 (R3-exact): gemm2 only, grid (16,32).
// ---------------------------------------------------------------------------
__global__ __launch_bounds__(256) void gemm_bt64(const bf16* __restrict__ A, int lda,
                                                 const bf16* __restrict__ Bt, int ldb,
                                                 void* __restrict__ C, int ldc,
                                                 const bf16* __restrict__ bias, int K,
                                                 const int* __restrict__ outflag) {
  __shared__ bf16 As[2][128 * 32];
  __shared__ bf16 Bs[2][64 * 32];
  int t = threadIdx.x;
  int w = t >> 6, lane = t & 63;
  int g = lane >> 4, c = lane & 15;
  int wm = (w >> 1) * 64, wn = (w & 1) * 32;
  int m0 = blockIdx.y * 128, n0 = blockIdx.x * 64;

  int sr = (lane >> 2);
  int sc = (lane & 3) * 8;
  const bf16* Ab = A + (size_t)(m0 + w * 32 + sr) * lda + sc;
  const bf16* Bb = Bt + (size_t)(n0 + w * 16 + sr) * ldb + sc;
  int laofs = (w * 32) * 32;
  int lbofs = (w * 16) * 32;

  floatx4 acc[4][2] = {};

  for (int k0 = 0; k0 < K; k0 += 64) {
    __syncthreads();
#pragma unroll
    for (int h = 0; h < 2; h++) {
      gll16(Ab + k0 + h * 32, &As[h][laofs]);
      gll16(Ab + k0 + h * 32 + (size_t)16 * lda, &As[h][laofs + 16 * 32]);
      gll16(Bb + k0 + h * 32, &Bs[h][lbofs]);
    }
    __syncthreads();
#pragma unroll
    for (int h = 0; h < 2; h++) {
      short8 af[4], bf[2];
#pragma unroll
      for (int i = 0; i < 4; i++)
        af[i] = *reinterpret_cast<const short8*>(&As[h][(wm + i * 16 + c) * 32 + g * 8]);
#pragma unroll
      for (int j = 0; j < 2; j++)
        bf[j] = *reinterpret_cast<const short8*>(&Bs[h][(wn + j * 16 + c) * 32 + g * 8]);
#pragma unroll
      for (int i = 0; i < 4; i++)
#pragma unroll
        for (int j = 0; j < 2; j++) acc[i][j] = MFMA16(af[i], bf[j], acc[i][j]);
    }
  }

  bool f32out = (outflag != nullptr) && (*outflag != 0);
#pragma unroll
  for (int i = 0; i < 4; i++) {
    int rbase = m0 + wm + i * 16 + g * 4;
#pragma unroll
    for (int j = 0; j < 2; j++) {
      int col = n0 + wn + j * 16 + c;
      float bv = bias ? __bfloat162float(bias[col]) : 0.f;
#pragma unroll
      for (int r = 0; r < 4; r++) {
        size_t off = (size_t)(rbase + r) * ldc + col;
        float v = acc[i][j][r] + bv;
        if (f32out) ((float*)C)[off] = v;
        else ((bf16*)C)[off] = __float2bfloat16(v);
      }
    }
  }
}

// ---------------------------------------------------------------------------
// R10 split-K causal attention (proven: 52.4 -> 43.6 us, occ 25 -> 42%).
// Fixed-offset softmax (exp2(s*scale-23.08), no running max) -> partials
// over disjoint k-ranges exactly additive; qt>=8 splits into 2 half-k
// blocks writing f32 partials; combine_k merges. 768 blocks = 3/CU; every
// block <= 16 tiles. Static LPT triple table (optimal for 2-way splits).
// XCD-local heads preserved (split halves read DISJOINT K/V ranges).
// Lessons kept OUT: permlane P-redistr (R4); V-direct-from-L2 (R5);
// QBLK=64 (R5); gemm restructures (R7/R8/R9/R11); diag-hoist (R11:
// codegen perturbation, occ 42->27).
// ---------------------------------------------------------------------------
__device__ const int QT_TAB[8][3] = {{15, 15, 0}, {7, 13, 1},  {14, 12, 2}, {14, 10, 3},
                                     {13, 4, 9},  {6, 10, 8},  {12, 11, 8}, {5, 11, 9}};
__device__ const int HF_TAB[8][3] = {{0, 1, 2}, {2, 0, 2}, {0, 0, 2}, {1, 0, 2},
                                     {1, 2, 0}, {2, 1, 0}, {1, 0, 1}, {2, 1, 1}};

__global__ __launch_bounds__(512, 4) void attn_lds2(bf16* __restrict__ QKV,
                                                    const bf16* __restrict__ VT,
                                                    float* __restrict__ Po,
                                                    float* __restrict__ Pl) {
  const int S = 2048, LD = 3072;
  __shared__ bf16 Ks[2][2][64 * 32];
  __shared__ bf16 Vs[2][2][64 * 32];
  __shared__ bf16 Pb[8][16 * 72];

  int t = threadIdx.x, w = t >> 6, lane = t & 63, g = lane >> 4, c = lane & 15;

  // slot decode: 768 blocks; co-resident CU triple = (r, r+256, r+512)
  int r = blockIdx.x + 24 * blockIdx.y;   // hw linear dispatch index
  int xcd = r & 7;
  int s = r >> 3;                          // 0..95 on this XCD
  int r3 = s >> 5;                         // ring 0..2 (CU triple member)
  int u = s & 31;                          // CU index on XCD
  int hg = u >> 3;                         // head group 0..3
  int tri = u & 7;                         // triple id
  int bh = xcd + 8 * hg;                   // XCD-local heads (4/XCD, 2MB K/V)
  int qt = QT_TAB[tri][r3];
  int hf = HF_TAB[tri][r3];                // 0/1 = split half, 2 = unsplit

  int b = bh >> 4, h = bh & 15;
  int qbase = qt * 128;
  size_t rowb = (size_t)b * S;
  int hq = h * 64, hk = 1024 + h * 64;
  const bf16* Vt = VT + (size_t)bh * 64 * 2048;
  bf16* pb = Pb[w];

  int nkt = 2 * qt + 2;
  int kb0 = (hf == 1) ? (qt + 1) : 0;
  int kb1 = (hf == 0) ? (qt + 1) : nkt;

  int su = (w & 3) * 16 + (lane >> 2);
  int sc = (lane & 3) * 8;
  const bf16* Kg = &QKV[(rowb + su) * LD + hk + sc];
  const bf16* Vg = &Vt[(size_t)su * 2048 + sc];
  int sofs = ((w & 3) * 16) * 32;

  short8 qf[2];
#pragma unroll
  for (int hfr = 0; hfr < 2; hfr++)
    qf[hfr] = *reinterpret_cast<const short8*>(
        &QKV[(rowb + qbase + w * 16 + c) * LD + hq + hfr * 32 + g * 8]);

  floatx4 o[4] = {};
  float lsum = 0.f;
  int qrow = qbase + w * 16 + c;  // this lane's q-row for the S^T fragment

  {
    size_t k0off = (size_t)kb0 * 64;
    if (w < 4) {
      gll16(Kg + k0off * LD, &Ks[0][0][sofs]);
      gll16(Kg + k0off * LD + 32, &Ks[0][1][sofs]);
    } else {
      gll16(Vg + k0off, &Vs[0][0][sofs]);
      gll16(Vg + k0off + 32, &Vs[0][1][sofs]);
    }
  }

  for (int kt = kb0; kt < kb1; kt++) {
    int kbase = kt * 64;
    int cur = (kt - kb0) & 1;
    __syncthreads();
    if (kt + 1 < kb1) {
      int nb = cur ^ 1;
      size_t kofs = (size_t)(kbase + 64);
      if (w < 4) {
        gll16(Kg + kofs * LD, &Ks[nb][0][sofs]);
        gll16(Kg + kofs * LD + 32, &Ks[nb][1][sofs]);
      } else {
        gll16(Vg + kofs, &Vs[nb][0][sofs]);
        gll16(Vg + kofs + 32, &Vs[nb][1][sofs]);
      }
    }

    short8 kf[4][2];
#pragma unroll
    for (int nt = 0; nt < 4; nt++)
#pragma unroll
      for (int hfr = 0; hfr < 2; hfr++)
        kf[nt][hfr] =
            *reinterpret_cast<const short8*>(&Ks[cur][hfr][(nt * 16 + c) * 32 + g * 8]);

    // S^T tile: sv[nt][rr] = S[k = kbase + nt*16 + g*4 + rr][q = qrow]
    floatx4 sv[4];
    __builtin_amdgcn_s_setprio(1);
#pragma unroll
    for (int nt = 0; nt < 4; nt++) {
      floatx4 z = {};
      z = MFMA16(kf[nt][0], qf[0], z);
      z = MFMA16(kf[nt][1], qf[1], z);
      sv[nt] = z;
    }
    __builtin_amdgcn_s_setprio(0);

    bool diag = (kbase + 63 > qbase + w * 16);
#pragma unroll
    for (int nt = 0; nt < 4; nt++) {
      int kcol0 = kbase + nt * 16 + g * 4;
#pragma unroll
      for (int rr = 0; rr < 4; rr++) {
        float arg = fmaf(sv[nt][rr], 0.18033688f, -23.083120f);
        if (diag && (kcol0 + rr > qrow)) arg = -1e30f;
        float p = exp2f(arg);
        lsum += p;
        sv[nt][rr] = p;
      }
    }

    // P[q=c][k]: each lane stores 4 consecutive k as one b64
#pragma unroll
    for (int nt = 0; nt < 4; nt++) {
      union { bf16 h4[4]; uint2 u2; } U;
      U.h4[0] = __float2bfloat16(sv[nt][0]);
      U.h4[1] = __float2bfloat16(sv[nt][1]);
      U.h4[2] = __float2bfloat16(sv[nt][2]);
      U.h4[3] = __float2bfloat16(sv[nt][3]);
      *reinterpret_cast<uint2*>(&pb[c * 72 + nt * 16 + g * 4]) = U.u2;
    }
    asm volatile("s_waitcnt lgkmcnt(0)" ::: "memory");
    short8 pf0 = *reinterpret_cast<const short8*>(&pb[c * 72 + g * 8]);
    short8 pf1 = *reinterpret_cast<const short8*>(&pb[c * 72 + 32 + g * 8]);

    __builtin_amdgcn_s_setprio(1);
#pragma unroll
    for (int dt = 0; dt < 4; dt++) {
      short8 vf0 = *reinterpret_cast<const short8*>(&Vs[cur][0][(dt * 16 + c) * 32 + g * 8]);
      short8 vf1 = *reinterpret_cast<const short8*>(&Vs[cur][1][(dt * 16 + c) * 32 + g * 8]);
      o[dt] = MFMA16(pf0, vf0, o[dt]);
      o[dt] = MFMA16(pf1, vf1, o[dt]);
    }
    __builtin_amdgcn_s_setprio(0);
  }

  // full row-sum for q-row c (butterfly over the 4 g-groups: all lanes get it)
  lsum += __shfl_xor(lsum, 16);
  lsum += __shfl_xor(lsum, 32);

  if (hf == 2) {
    float lrec = 1.0f / lsum;
    float l_r[4];
#pragma unroll
    for (int rr = 0; rr < 4; rr++) l_r[rr] = __shfl(lrec, g * 4 + rr);
#pragma unroll
    for (int dt = 0; dt < 4; dt++)
#pragma unroll
      for (int rr = 0; rr < 4; rr++) {
        float v = o[dt][rr] * l_r[rr];
        QKV[(rowb + qbase + w * 16 + g * 4 + rr) * LD + hq + dt * 16 + c] =
            __float2bfloat16(v);
      }
  } else {
    // write raw partials (additive): o f32 + per-row lsum
    int slot = (bh * 8 + (qt - 8)) * 2 + hf;
    float* po = Po + (size_t)slot * (128 * 64);
    float* pl = Pl + slot * 128;
    if (g == 0) pl[w * 16 + c] = lsum;
#pragma unroll
    for (int dt = 0; dt < 4; dt++)
#pragma unroll
      for (int rr = 0; rr < 4; rr++)
        po[(w * 16 + g * 4 + rr) * 64 + dt * 16 + c] = o[dt][rr];
  }
}

// ---------------------------------------------------------------------------
// Combine split-K partials: out = (oA+oB)/(lA+lB) -> Q region bf16.
// grid (8 qt-slots, 32 bh), 256 thr.
// ---------------------------------------------------------------------------
__global__ __launch_bounds__(256) void combine_k(const float* __restrict__ Po,
                                                 const float* __restrict__ Pl,
                                                 bf16* __restrict__ QKV) {
  int qi = blockIdx.x;        // qt = 8 + qi
  int bh = blockIdx.y;
  int b = bh >> 4, h = bh & 15;
  int qt = 8 + qi;
  int slot = (bh * 8 + qi) * 2;
  const float* oA = Po + (size_t)slot * (128 * 64);
  const float* oB = oA + 128 * 64;
  const float* lA = Pl + slot * 128;
  const float* lB = lA + 128;
  int t = threadIdx.x;
#pragma unroll
  for (int i = 0; i < 32; i++) {
    int idx = t + i * 256;    // 0..8191
    int row = idx >> 6, d = idx & 63;
    float l = lA[row] + lB[row];
    float v = (oA[idx] + oB[idx]) / l;
    QKV[((size_t)b * 2048 + qt * 128 + row) * 3072 + h * 64 + d] = __float2bfloat16(v);
  }
}

// ---------------------------------------------------------------------------
extern "C" void kernel_launch(void* const* d_in, const int* in_sizes, int n_in,
                              void* d_out, int out_size, void* d_ws, size_t ws_size,
                              hipStream_t stream) {
  char* ws = (char*)d_ws;
  const size_t MB = 1024 * 1024;
  int* flag = (int*)ws;                       // 4 B
  bf16* bias = (bf16*)(ws + 4096);            // 2 KB
  bf16* xb = (bf16*)(ws + 1 * MB);            // [4096][1024]  8 MB (reused as VT)
  bf16* Wt = (bf16*)(ws + 9 * MB);            // [3072][1024]  6 MB
  bf16* Wpt = (bf16*)(ws + 15 * MB);          // [1024][1024]  2 MB
  bf16* QKV = (bf16*)(ws + 17 * MB);          // [4096][3072] 24 MB
  bf16* VT = xb;                              // xb dead after gemm1
  // split-K partials: o needs 32*8*2*128*64*4 = 16 MB. d_out (f32 out =
  // 16 MB) is dead until gemm2 -> reuse it when big enough; else ws tail.
  float* Pl = (float*)(ws + 41 * MB);         // 256 KB lsum partials
  float* Po = (out_size >= (int)(16 * MB)) ? (float*)d_out
                                           : (float*)(ws + 42 * MB);

  detect_bias_k<<<1, 256, 0, stream>>>((const unsigned short*)d_in[0], d_in[5], bias, flag);
  prep_k<<<dim3(32, 32, 6), dim3(32, 8), 0, stream>>>(d_in[0], xb, d_in[1], d_in[2],
                                                      d_in[3], d_in[4], Wt, Wpt, flag);

  // QKV = xb @ [Wq|Wk|Wv] : M=4096, N=3072, K=1024 (R3-proven config)
  gemm_bt128<<<dim3(24, 32), 256, 0, stream>>>(xb, 1024, Wt, 1024, QKV, 3072, nullptr,
                                               1024, nullptr);
  // V^T into (dead) xb region
  vtrans_k<<<dim3(32, 32), dim3(64, 8), 0, stream>>>(QKV, VT);
  // split-K attention: 768 blocks, every block <= 16 k-tiles
  attn_lds2<<<dim3(24, 32), 512, 0, stream>>>(QKV, VT, Po, Pl);
  // merge split partials into Q region
  combine_k<<<dim3(8, 32), 256, 0, stream>>>(Po, Pl, QKV);
  // out = attn_out @ Wp + bp : M=4096, N=1024, K=1024 (overwrites d_out/Po)
  gemm_bt64<<<dim3(16, 32), 256, 0, stream>>>(QKV, 3072, Wpt, 1024, d_out, 1024, bias,
                                              1024, flag);
}